// Round 1
// baseline (623.345 us; speedup 1.0000x reference)
//
#include <hip/hip_runtime.h>

// FactorizedQuantizedDistribution:
//   params [B, 255, H, W] f32 tree-node logits, sample [B, H, W] f32 in [0,1)
//   out[b] = sum_{h,w} sum_{x=0..7} v*logit - softplus(logit) along the tree path.
// Tree path: node_0 = 0; node_{x+1} = 2*node_x + 1 + bit_x (bits MSB-first of
// uint8(sample*256)). Path depends only on sample -> all 8 gathers independent.

#define NBITS 8

__global__ __launch_bounds__(256) void fqd_kernel(
    const float* __restrict__ params,   // [B, 255, P] (P = H*W)
    const float* __restrict__ sample,   // [B, P]
    float* __restrict__ out,            // [B]
    int P)                              // pixels per batch (65536)
{
    const int b = blockIdx.y;
    const int t = blockIdx.x * blockDim.x + threadIdx.x;   // one thread = 4 pixels
    const int pix0 = t * 4;

    const float4 smp = *reinterpret_cast<const float4*>(
        sample + (size_t)b * P + pix0);
    const float* pbase = params + (size_t)b * 255 * (size_t)P + pix0;

    unsigned s[4];
    s[0] = (unsigned)(smp.x * 256.0f) & 255u;
    s[1] = (unsigned)(smp.y * 256.0f) & 255u;
    s[2] = (unsigned)(smp.z * 256.0f) & 255u;
    s[3] = (unsigned)(smp.w * 256.0f) & 255u;

    // Phase 1: issue all 32 gathers (addresses depend only on sample bits).
    float logits[4][NBITS];
    unsigned bits[4];   // bit x of pixel p lives at bit (7-x) of s[p] already
#pragma unroll
    for (int p = 0; p < 4; ++p) {
        unsigned sv = s[p];
        int node = 0;
#pragma unroll
        for (int x = 0; x < NBITS; ++x) {
            logits[p][x] = pbase[(size_t)node * P + p];
            unsigned bit = (sv >> (NBITS - 1 - x)) & 1u;
            node = 2 * node + 1 + (int)bit;
        }
        bits[p] = sv;
    }

    // Phase 2: math. v*x - softplus(x) = (bit ? min(x,0) : -max(x,0)) - log1p(exp(-|x|))
    float sum = 0.0f;
#pragma unroll
    for (int p = 0; p < 4; ++p) {
        unsigned sv = bits[p];
#pragma unroll
        for (int x = 0; x < NBITS; ++x) {
            float lg = logits[p][x];
            unsigned bit = (sv >> (NBITS - 1 - x)) & 1u;
            float lin = bit ? fminf(lg, 0.0f) : -fmaxf(lg, 0.0f);
            sum += lin - log1pf(__expf(-fabsf(lg)));
        }
    }

    // Wave (64-lane) shuffle reduction, then LDS across the 4 waves, then atomic.
#pragma unroll
    for (int off = 32; off > 0; off >>= 1)
        sum += __shfl_down(sum, off, 64);

    __shared__ float red[4];
    const int lane = threadIdx.x & 63;
    const int wid  = threadIdx.x >> 6;
    if (lane == 0) red[wid] = sum;
    __syncthreads();
    if (threadIdx.x == 0) {
        float tot = red[0] + red[1] + red[2] + red[3];
        atomicAdd(out + b, tot);
    }
}

extern "C" void kernel_launch(void* const* d_in, const int* in_sizes, int n_in,
                              void* d_out, int out_size, void* d_ws, size_t ws_size,
                              hipStream_t stream) {
    const float* params = (const float*)d_in[0];
    const float* sample = (const float*)d_in[1];
    float* out = (float*)d_out;

    const int B = out_size;                    // 8
    const int P = in_sizes[1] / B;             // 65536 pixels per batch

    // d_out is poisoned 0xAA before every call; zero it for the atomics.
    hipMemsetAsync(d_out, 0, (size_t)out_size * sizeof(float), stream);

    const int threads = 256;
    const int pix_per_block = threads * 4;     // 1024
    dim3 grid(P / pix_per_block, B);           // (64, 8)
    fqd_kernel<<<grid, threads, 0, stream>>>(params, sample, out, P);
}

// Round 2
// 612.225 us; speedup vs baseline: 1.0182x; 1.0182x over previous
//
#include <hip/hip_runtime.h>

// FactorizedQuantizedDistribution:
//   params [B, 255, H, W] f32 tree-node logits, sample [B, H, W] f32 in [0,1)
//   out[b] = sum_{h,w} sum_{x=0..7} v*logit - softplus(logit) along the tree path.
// Tree path: node_0 = 0; node_{x+1} = 2*node_x + 1 + bit_x (bits MSB-first of
// uint8(sample*256)). Path depends only on sample -> all 8 gathers independent.
//
// R1: 1 pixel/thread (was 4). 8192 waves = 32 waves/CU (max occupancy) to hide
// scattered-gather latency; per-CU outstanding loads unchanged, register
// pressure way down. __launch_bounds__(256,8) = 8 waves/EU -> VGPR cap 64.

#define NBITS 8

__global__ __launch_bounds__(256, 8) void fqd_kernel(
    const float* __restrict__ params,   // [B, 255, P] (P = H*W)
    const float* __restrict__ sample,   // [B, P]
    float* __restrict__ out,            // [B]
    int P)                              // pixels per batch (65536)
{
    const int b = blockIdx.y;
    const int pix = blockIdx.x * blockDim.x + threadIdx.x;   // one thread = 1 pixel

    const float sv_f = sample[(size_t)b * P + pix];
    const unsigned sv = (unsigned)(sv_f * 256.0f) & 255u;

    const float* pbase = params + (size_t)b * 255 * (size_t)P + pix;

    // Phase 1: issue all 8 gathers (addresses depend only on sample bits).
    float lg[NBITS];
    {
        int node = 0;
#pragma unroll
        for (int x = 0; x < NBITS; ++x) {
            lg[x] = pbase[(size_t)node * P];
            node = 2 * node + 1 + (int)((sv >> (NBITS - 1 - x)) & 1u);
        }
    }

    // Phase 2: v*x - softplus(x) = (bit ? min(x,0) : -max(x,0)) - log1p(exp(-|x|))
    float sum = 0.0f;
#pragma unroll
    for (int x = 0; x < NBITS; ++x) {
        const float l = lg[x];
        const unsigned bit = (sv >> (NBITS - 1 - x)) & 1u;
        const float lin = bit ? fminf(l, 0.0f) : -fmaxf(l, 0.0f);
        sum += lin - log1pf(__expf(-fabsf(l)));
    }

    // Wave (64-lane) shuffle reduction, then LDS across the 4 waves, then atomic.
#pragma unroll
    for (int off = 32; off > 0; off >>= 1)
        sum += __shfl_down(sum, off, 64);

    __shared__ float red[4];
    const int lane = threadIdx.x & 63;
    const int wid  = threadIdx.x >> 6;
    if (lane == 0) red[wid] = sum;
    __syncthreads();
    if (threadIdx.x == 0) {
        float tot = red[0] + red[1] + red[2] + red[3];
        atomicAdd(out + b, tot);
    }
}

extern "C" void kernel_launch(void* const* d_in, const int* in_sizes, int n_in,
                              void* d_out, int out_size, void* d_ws, size_t ws_size,
                              hipStream_t stream) {
    const float* params = (const float*)d_in[0];
    const float* sample = (const float*)d_in[1];
    float* out = (float*)d_out;

    const int B = out_size;                    // 8
    const int P = in_sizes[1] / B;             // 65536 pixels per batch

    // d_out is poisoned 0xAA before every call; zero it for the atomics.
    hipMemsetAsync(d_out, 0, (size_t)out_size * sizeof(float), stream);

    const int threads = 256;
    dim3 grid(P / threads, B);                 // (256, 8) = 2048 blocks
    fqd_kernel<<<grid, threads, 0, stream>>>(params, sample, out, P);
}